// Round 1
// baseline (155.138 us; speedup 1.0000x reference)
//
#include <hip/hip_runtime.h>

// EmbeddingDistance: out[b] = 1 - dot(mean_i norm(x1[b,i,:]), mean_j norm(x2[b,j,:]))
// x1, x2: (16, 4096, 256) fp32.  Memory-bound: 134 MB read.

constexpr int D = 256;            // embedding dim
constexpr int S = 4096;           // segments (rows) per batch
constexpr int B = 16;             // batches
constexpr int BLOCKS_PER_PAIR = 32;
constexpr int WAVES_PER_BLOCK = 4;              // 256 threads
constexpr int WAVES_PER_PAIR  = BLOCKS_PER_PAIR * WAVES_PER_BLOCK;  // 128
constexpr int ROWS_PER_WAVE   = S / WAVES_PER_PAIR;                 // 32
constexpr float EPS = 1e-8f;

// Kernel 1: one wave per row.  lane l holds dims [4l, 4l+4) as float4.
// Accumulates normalized rows into a register float4, reduces across the
// block's 4 waves via LDS, then one atomicAdd per (pair, dim) element.
__global__ __launch_bounds__(256) void row_norm_sum_kernel(
    const float* __restrict__ x1, const float* __restrict__ x2,
    float* __restrict__ sums /* [2*B][D] : pair = batch*2 + input */)
{
    const int pair = blockIdx.x / BLOCKS_PER_PAIR;      // 0..31
    const int blk  = blockIdx.x % BLOCKS_PER_PAIR;      // 0..31
    const int w    = threadIdx.x >> 6;                  // 0..3
    const int lane = threadIdx.x & 63;
    const int wv   = blk * WAVES_PER_BLOCK + w;         // 0..127 within pair

    const int batch = pair >> 1;
    const float* __restrict__ src = (pair & 1) ? x2 : x1;
    src += (size_t)batch * S * D;

    float4 acc = make_float4(0.f, 0.f, 0.f, 0.f);

    // 32 rows per wave, strided so the 128 waves of a pair read 128
    // consecutive rows (128 KB contiguous) at each step.  Unroll 2 for ILP.
    #pragma unroll
    for (int i = 0; i < ROWS_PER_WAVE; i += 2) {
        const int r0 = wv + (i + 0) * WAVES_PER_PAIR;
        const int r1 = wv + (i + 1) * WAVES_PER_PAIR;
        const float4 v0 = *(const float4*)(src + (size_t)r0 * D + lane * 4);
        const float4 v1 = *(const float4*)(src + (size_t)r1 * D + lane * 4);

        float ss0 = v0.x * v0.x + v0.y * v0.y + v0.z * v0.z + v0.w * v0.w;
        float ss1 = v1.x * v1.x + v1.y * v1.y + v1.z * v1.z + v1.w * v1.w;
        #pragma unroll
        for (int m = 1; m < 64; m <<= 1) {
            ss0 += __shfl_xor(ss0, m, 64);
            ss1 += __shfl_xor(ss1, m, 64);
        }
        const float s0 = 1.0f / fmaxf(sqrtf(ss0), EPS);
        const float s1 = 1.0f / fmaxf(sqrtf(ss1), EPS);
        acc.x += v0.x * s0 + v1.x * s1;
        acc.y += v0.y * s0 + v1.y * s1;
        acc.z += v0.z * s0 + v1.z * s1;
        acc.w += v0.w * s0 + v1.w * s1;
    }

    // Block reduction: wave w writes its 256 partials, then 256 threads each
    // sum 4 values (conflict-free reads: consecutive t -> consecutive banks).
    __shared__ float lds[WAVES_PER_BLOCK][D];
    *(float4*)&lds[w][lane * 4] = acc;
    __syncthreads();

    const int t = threadIdx.x;
    const float v = lds[0][t] + lds[1][t] + lds[2][t] + lds[3][t];
    atomicAdd(&sums[(size_t)pair * D + t], v);
}

// Kernel 2: out[b] = 1 - dot(sum1, sum2) / S^2.  One wave per batch.
__global__ __launch_bounds__(64) void finalize_kernel(
    const float* __restrict__ sums, float* __restrict__ out)
{
    const int b = blockIdx.x;
    const int lane = threadIdx.x;
    const float4 a = *(const float4*)(sums + (size_t)(2 * b + 0) * D + lane * 4);
    const float4 c = *(const float4*)(sums + (size_t)(2 * b + 1) * D + lane * 4);
    float d = a.x * c.x + a.y * c.y + a.z * c.z + a.w * c.w;
    #pragma unroll
    for (int m = 1; m < 64; m <<= 1) d += __shfl_xor(d, m, 64);
    if (lane == 0) {
        const float inv = 1.0f / ((float)S * (float)S);
        out[b] = 1.0f - d * inv;
    }
}

extern "C" void kernel_launch(void* const* d_in, const int* in_sizes, int n_in,
                              void* d_out, int out_size, void* d_ws, size_t ws_size,
                              hipStream_t stream) {
    const float* x1 = (const float*)d_in[0];
    const float* x2 = (const float*)d_in[1];
    float* out = (float*)d_out;
    float* sums = (float*)d_ws;                       // 2*B*D floats = 32 KB

    hipMemsetAsync(sums, 0, (size_t)2 * B * D * sizeof(float), stream);

    row_norm_sum_kernel<<<2 * B * BLOCKS_PER_PAIR, 256, 0, stream>>>(x1, x2, sums);
    finalize_kernel<<<B, 64, 0, stream>>>(sums, out);
}

// Round 2
// 146.188 us; speedup vs baseline: 1.0612x; 1.0612x over previous
//
#include <hip/hip_runtime.h>

// EmbeddingDistance: out[b] = 1 - dot(mean_i norm(x1[b,i,:]), mean_j norm(x2[b,j,:]))
// x1, x2: (16, 4096, 256) fp32.  134 MB input, L3-resident on replays ->
// latency-bound, not HBM-bound.  Max occupancy + 4-wide ILP.

constexpr int D = 256;            // embedding dim
constexpr int S = 4096;           // segments (rows) per batch
constexpr int B = 16;             // batches
constexpr int BLOCKS_PER_PAIR = 64;
constexpr int WAVES_PER_BLOCK = 4;              // 256 threads
constexpr int WAVES_PER_PAIR  = BLOCKS_PER_PAIR * WAVES_PER_BLOCK;  // 256
constexpr int ROWS_PER_WAVE   = S / WAVES_PER_PAIR;                 // 16
constexpr int NPAIR = 2 * B;                                        // 32
constexpr int NBLK1 = NPAIR * BLOCKS_PER_PAIR;                      // 2048
constexpr float EPS2 = 1e-16f;    // eps^2 for the norm clamp

// ---- Kernel 1: one wave per row, lane l owns dims [4l, 4l+4).
// Unroll 4 rows -> 4 independent load+shfl chains.  Block-level LDS
// reduction, then either a partial-store (preferred) or atomicAdd.
template <bool USE_PARTIALS>
__global__ __launch_bounds__(256) void row_norm_sum_kernel(
    const float* __restrict__ x1, const float* __restrict__ x2,
    float* __restrict__ sums /* USE_PARTIALS ? [NBLK1][D] : [NPAIR][D] */)
{
    const int pair = blockIdx.x / BLOCKS_PER_PAIR;      // 0..31
    const int blk  = blockIdx.x % BLOCKS_PER_PAIR;      // 0..63
    const int w    = threadIdx.x >> 6;                  // 0..3
    const int lane = threadIdx.x & 63;
    const int wv   = blk * WAVES_PER_BLOCK + w;         // 0..255 within pair

    const int batch = pair >> 1;
    const float* __restrict__ src = (pair & 1) ? x2 : x1;
    src += (size_t)batch * S * D;

    float4 acc = make_float4(0.f, 0.f, 0.f, 0.f);

    #pragma unroll
    for (int i = 0; i < ROWS_PER_WAVE; i += 4) {
        float4 v[4];
        float  ss[4];
        #pragma unroll
        for (int k = 0; k < 4; ++k) {
            const int r = wv + (i + k) * WAVES_PER_PAIR;
            v[k] = *(const float4*)(src + (size_t)r * D + lane * 4);
        }
        #pragma unroll
        for (int k = 0; k < 4; ++k)
            ss[k] = v[k].x * v[k].x + v[k].y * v[k].y
                  + v[k].z * v[k].z + v[k].w * v[k].w;
        // 4 independent butterfly chains (6 steps each) — latency overlaps.
        #pragma unroll
        for (int m = 1; m < 64; m <<= 1) {
            #pragma unroll
            for (int k = 0; k < 4; ++k)
                ss[k] += __shfl_xor(ss[k], m, 64);
        }
        #pragma unroll
        for (int k = 0; k < 4; ++k) {
            const float s = rsqrtf(fmaxf(ss[k], EPS2));
            acc.x += v[k].x * s;
            acc.y += v[k].y * s;
            acc.z += v[k].z * s;
            acc.w += v[k].w * s;
        }
    }

    // Block reduction across the 4 waves.
    __shared__ float lds[WAVES_PER_BLOCK][D];
    *(float4*)&lds[w][lane * 4] = acc;
    __syncthreads();

    const int t = threadIdx.x;
    const float val = lds[0][t] + lds[1][t] + lds[2][t] + lds[3][t];
    if (USE_PARTIALS) {
        sums[(size_t)blockIdx.x * D + t] = val;     // no atomics, no memset
    } else {
        atomicAdd(&sums[(size_t)pair * D + t], val);
    }
}

// ---- Kernel 2 (partials path): per batch, reduce 64-block partials for both
// inputs, dot them, block-reduce, write 1 - dot/S^2.
__global__ __launch_bounds__(256) void finalize_partials_kernel(
    const float* __restrict__ partials, float* __restrict__ out)
{
    const int b = blockIdx.x;
    const int t = threadIdx.x;
    const int w = t >> 6, lane = t & 63;

    const float* p1 = partials + ((size_t)(2 * b + 0) * BLOCKS_PER_PAIR) * D + t;
    const float* p2 = partials + ((size_t)(2 * b + 1) * BLOCKS_PER_PAIR) * D + t;
    float s1 = 0.f, s2 = 0.f;
    #pragma unroll 8
    for (int k = 0; k < BLOCKS_PER_PAIR; ++k) {
        s1 += p1[(size_t)k * D];
        s2 += p2[(size_t)k * D];
    }
    float d = s1 * s2;
    #pragma unroll
    for (int m = 1; m < 64; m <<= 1) d += __shfl_xor(d, m, 64);

    __shared__ float r[WAVES_PER_BLOCK];
    if (lane == 0) r[w] = d;
    __syncthreads();
    if (t == 0) {
        const float inv = 1.0f / ((float)S * (float)S);
        out[b] = 1.0f - (r[0] + r[1] + r[2] + r[3]) * inv;
    }
}

// ---- Kernel 2 (atomic fallback path): sums are already fully reduced.
__global__ __launch_bounds__(64) void finalize_kernel(
    const float* __restrict__ sums, float* __restrict__ out)
{
    const int b = blockIdx.x;
    const int lane = threadIdx.x;
    const float4 a = *(const float4*)(sums + (size_t)(2 * b + 0) * D + lane * 4);
    const float4 c = *(const float4*)(sums + (size_t)(2 * b + 1) * D + lane * 4);
    float d = a.x * c.x + a.y * c.y + a.z * c.z + a.w * c.w;
    #pragma unroll
    for (int m = 1; m < 64; m <<= 1) d += __shfl_xor(d, m, 64);
    if (lane == 0) {
        const float inv = 1.0f / ((float)S * (float)S);
        out[b] = 1.0f - d * inv;
    }
}

extern "C" void kernel_launch(void* const* d_in, const int* in_sizes, int n_in,
                              void* d_out, int out_size, void* d_ws, size_t ws_size,
                              hipStream_t stream) {
    const float* x1 = (const float*)d_in[0];
    const float* x2 = (const float*)d_in[1];
    float* out = (float*)d_out;
    float* ws = (float*)d_ws;

    const size_t partial_bytes = (size_t)NBLK1 * D * sizeof(float);   // 2 MB
    if (ws_size >= partial_bytes) {
        row_norm_sum_kernel<true><<<NBLK1, 256, 0, stream>>>(x1, x2, ws);
        finalize_partials_kernel<<<B, 256, 0, stream>>>(ws, out);
    } else {
        hipMemsetAsync(ws, 0, (size_t)NPAIR * D * sizeof(float), stream);
        row_norm_sum_kernel<false><<<NBLK1, 256, 0, stream>>>(x1, x2, ws);
        finalize_kernel<<<B, 64, 0, stream>>>(ws, out);
    }
}